// Round 3
// baseline (572.945 us; speedup 1.0000x reference)
//
#include <hip/hip_runtime.h>
#include <hip/hip_bf16.h>
#include <cstdint>

#define NV 3
#define NN 4096
#define HH 256
#define CC 20
#define DYY 300
#define DD 512

typedef __bf16 v8bf  __attribute__((ext_vector_type(8)));
typedef float  v16f  __attribute__((ext_vector_type(16)));

static __device__ __forceinline__ float bf2f(unsigned short u) {
    union { unsigned int i; float f; } c; c.i = ((unsigned int)u) << 16; return c.f;
}

// Stage a 128x64 bf16 tile into a 16 KB LDS buffer via global_load_lds w=16.
// LDS dest linear (HW requirement); XOR swizzle (chunk ^= row&7) applied on the
// GLOBAL source side, matching XOR on ds_read (rule #21).
static __device__ __forceinline__ void stage_tile(const __bf16* src, int strideElems,
                                                  char* lds, int tid)
{
#pragma unroll
    for (int i = 0; i < 4; ++i) {
        int id = i * 256 + tid;          // 16 B chunk id, 0..1023
        int r = id >> 3, c = id & 7;
        const char* g = (const char*)(src + (size_t)r * strideElems)
                        + ((c ^ (r & 7)) << 4);
        __builtin_amdgcn_global_load_lds(
            (const __attribute__((address_space(1))) unsigned int*)g,
            (__attribute__((address_space(3))) unsigned int*)(lds + id * 16),
            16, 0, 0);
    }
}

static __device__ __forceinline__ v8bf frag_read(const char* lds, int ra, int q)
{
    return *(const v8bf*)(lds + ra * 128 + ((q ^ (ra & 7)) << 4));
}

// ---------------------------------------------------------------- k_yn
__global__ __launch_bounds__(256) void k_yn(
    const float* __restrict__ y, const float* __restrict__ Wy,
    const float* __restrict__ by, float* __restrict__ YN)
{
    __shared__ __align__(16) float ysh[DYY];
    int c = blockIdx.x, tid = threadIdx.x;
    for (int i = tid; i < DYY; i += 256) ysh[i] = y[c * DYY + i];
    __syncthreads();
    float acc = by[tid];
    const float4* Wr4 = (const float4*)(Wy + (size_t)tid * DYY);
    const float4* ys4 = (const float4*)ysh;
    for (int d4 = 0; d4 < DYY / 4; ++d4) {
        float4 w = Wr4[d4], yy = ys4[d4];
        acc = fmaf(yy.x, w.x, acc); acc = fmaf(yy.y, w.y, acc);
        acc = fmaf(yy.z, w.z, acc); acc = fmaf(yy.w, w.w, acc);
    }
    YN[c * HH + tid] = 1.0f / (1.0f + __expf(-acc));
}

// ---------------------------------------------------------------- k_proj
__global__ __launch_bounds__(256) void k_proj(
    const float* __restrict__ x0, const float* __restrict__ x1, const float* __restrict__ x2,
    const float* __restrict__ W0, const float* __restrict__ W1, const float* __restrict__ W2,
    const float* __restrict__ b0, const float* __restrict__ b1, const float* __restrict__ b2,
    const int* __restrict__ mask,
    float* __restrict__ XP, __hip_bfloat16* __restrict__ XQh,
    __hip_bfloat16* __restrict__ XPMT)
{
    const int R = 8;
    int tid = threadIdx.x;
    int blk = blockIdx.x;
    int v  = blk / (NN / R);
    int n0 = (blk % (NN / R)) * R;
    const float* xv = (v == 0) ? x0 : (v == 1 ? x1 : x2);
    const float* Wv = (v == 0) ? W0 : (v == 1 ? W1 : W2);
    const float* bv = (v == 0) ? b0 : (v == 1 ? b1 : b2);

    __shared__ __align__(16) float xsh[R][DD];
    __shared__ float wred[4][R];
    __shared__ float nrm_sh[R];
    __shared__ int   msk_sh[R];

    const float4* xsrc = (const float4*)(xv + (size_t)n0 * DD);
    for (int i = tid; i < R * DD / 4; i += 256)
        ((float4*)xsh)[i] = xsrc[i];
    if (tid < R) msk_sh[tid] = mask[(n0 + tid) * NV + v];
    __syncthreads();

    float acc[R];
#pragma unroll
    for (int r = 0; r < R; ++r) acc[r] = 0.0f;
    const float4* Wrow = (const float4*)(Wv + (size_t)tid * DD);
    for (int d4 = 0; d4 < DD / 4; ++d4) {
        float4 w = Wrow[d4];
#pragma unroll
        for (int r = 0; r < R; ++r) {
            acc[r] = fmaf(xsh[r][4 * d4 + 0], w.x, acc[r]);
            acc[r] = fmaf(xsh[r][4 * d4 + 1], w.y, acc[r]);
            acc[r] = fmaf(xsh[r][4 * d4 + 2], w.z, acc[r]);
            acc[r] = fmaf(xsh[r][4 * d4 + 3], w.w, acc[r]);
        }
    }
    float bb = bv[tid];
    float vals[R];
#pragma unroll
    for (int r = 0; r < R; ++r) {
        float t = acc[r] + bb;
        vals[r] = (t >= 0.0f) ? t : 0.1f * t;
    }
    int lane = tid & 63, wv = tid >> 6;
#pragma unroll
    for (int r = 0; r < R; ++r) {
        float sq = vals[r] * vals[r];
#pragma unroll
        for (int off = 32; off > 0; off >>= 1)
            sq += __shfl_down(sq, off, 64);
        if (lane == 0) wred[wv][r] = sq;
    }
    __syncthreads();
    if (tid < R) {
        float s = wred[0][tid] + wred[1][tid] + wred[2][tid] + wred[3][tid];
        nrm_sh[tid] = fmaxf(sqrtf(s), 1e-12f);
    }
    __syncthreads();
    union { __hip_bfloat16 h[8]; uint4 u; } pk;
#pragma unroll
    for (int r = 0; r < R; ++r) {
        size_t o = ((size_t)v * NN + n0 + r) * HH + tid;
        float xpv = vals[r];
        XP[o]  = xpv;
        XQh[o] = __float2bfloat16(xpv / nrm_sh[r]);
        pk.h[r] = __float2bfloat16(msk_sh[r] ? xpv : 0.0f);
    }
    *(uint4*)&XPMT[((size_t)v * HH + tid) * NN + n0] = pk.u;
}

// ---------------------------------------------------------------- k_scores
// Upper-triangular 128x128 tiles, mirror-write transpose. 2-phase dbuf
// pipeline: stage(s+1) issued BEFORE compute(s); one drain per phase.
__global__ __launch_bounds__(256) void k_scores(
    const __hip_bfloat16* __restrict__ XQh, const int* __restrict__ mask,
    __hip_bfloat16* __restrict__ Sb)
{
    const int T = NN / 128;
    int rem = blockIdx.x, bi = 0;
    while (rem >= T - bi) { rem -= T - bi; ++bi; }
    int bj = bi + rem;
    int n0 = bi * 128, m0 = bj * 128;

    int tid = threadIdx.x, lane = tid & 63, wid = tid >> 6;
    int wr = (wid >> 1) * 64, wc = (wid & 1) * 64;
    int rowA = lane & 31, hi = lane >> 5;

    __shared__ __align__(128) char Ash[2][16384];
    __shared__ __align__(128) char Bsh[2][16384];
    __shared__ int mnsh[NV][128], mmsh[NV][128];

    if (tid < 128) {
#pragma unroll
        for (int v = 0; v < NV; ++v) {
            mnsh[v][tid] = mask[(n0 + tid) * NV + v];
            mmsh[v][tid] = mask[(m0 + tid) * NV + v];
        }
    }

    float comb[2][2][16];
#pragma unroll
    for (int i = 0; i < 2; ++i)
#pragma unroll
        for (int j = 0; j < 2; ++j)
#pragma unroll
            for (int r = 0; r < 16; ++r) comb[i][j][r] = -1e30f;

    v16f acc[2][2];
#pragma unroll
    for (int i = 0; i < 2; ++i)
#pragma unroll
        for (int j = 0; j < 2; ++j) acc[i][j] = (v16f)0.0f;

    const __bf16* Abase = (const __bf16*)XQh + (size_t)n0 * HH;
    const __bf16* Bbase = (const __bf16*)XQh + (size_t)m0 * HH;
    const size_t vstep = (size_t)NN * HH;

    // s = v*4 + kt, k0 = kt*64
    stage_tile(Abase, HH, Ash[0], tid);
    stage_tile(Bbase, HH, Bsh[0], tid);
    __syncthreads();

    int cur = 0;
#pragma unroll 1
    for (int s = 0; s < 12; ++s) {
        if (s < 11) {
            int sn = s + 1, vn = sn >> 2, kn = (sn & 3) * 64;
            stage_tile(Abase + (size_t)vn * vstep + kn, HH, Ash[cur ^ 1], tid);
            stage_tile(Bbase + (size_t)vn * vstep + kn, HH, Bsh[cur ^ 1], tid);
        }
#pragma unroll
        for (int kk = 0; kk < 4; ++kk) {
            int q = kk * 2 + hi;
            v8bf af[2], bfr[2];
#pragma unroll
            for (int t = 0; t < 2; ++t) {
                af[t]  = frag_read(Ash[cur], wr + t * 32 + rowA, q);
                bfr[t] = frag_read(Bsh[cur], wc + t * 32 + rowA, q);
            }
#pragma unroll
            for (int i = 0; i < 2; ++i)
#pragma unroll
                for (int j = 0; j < 2; ++j)
                    acc[i][j] = __builtin_amdgcn_mfma_f32_32x32x16_bf16(
                        af[i], bfr[j], acc[i][j], 0, 0, 0);
        }
        if ((s & 3) == 3) {
            int v = s >> 2;
#pragma unroll
            for (int i = 0; i < 2; ++i)
#pragma unroll
                for (int j = 0; j < 2; ++j) {
                    int cm = mmsh[v][wc + j * 32 + rowA];
#pragma unroll
                    for (int r = 0; r < 16; ++r) {
                        int rown = wr + i * 32 + (r & 3) + 8 * (r >> 2) + 4 * hi;
                        float g = (cm && mnsh[v][rown]) ? acc[i][j][r] : -1e30f;
                        comb[i][j][r] = fmaxf(comb[i][j][r], g);
                    }
                    acc[i][j] = (v16f)0.0f;
                }
        }
        __syncthreads();
        cur ^= 1;
    }

#pragma unroll
    for (int i = 0; i < 2; ++i)
#pragma unroll
        for (int j = 0; j < 2; ++j) {
            int m = m0 + wc + j * 32 + rowA;
            float sv[16];
#pragma unroll
            for (int r = 0; r < 16; ++r) {
                int rown = wr + i * 32 + (r & 3) + 8 * (r >> 2) + 4 * hi;
                float e = __expf(comb[i][j][r] * 5.0f);
                if (n0 + rown == m) e = 0.0f;
                sv[r] = e;
                Sb[(size_t)(n0 + rown) * NN + m] = __float2bfloat16(e);
            }
            if (bi != bj) {
#pragma unroll
                for (int g4 = 0; g4 < 4; ++g4) {
                    union { __hip_bfloat16 h[4]; uint2 u; } pk;
#pragma unroll
                    for (int j2 = 0; j2 < 4; ++j2)
                        pk.h[j2] = __float2bfloat16(sv[4 * g4 + j2]);
                    int nbase = n0 + wr + i * 32 + 8 * g4 + 4 * hi;
                    *(uint2*)((unsigned short*)Sb + (size_t)m * NN + nbase) = pk.u;
                }
            }
        }
}

// ---------------------------------------------------------------- k_rowstats
// Mask ballot-packed to LDS bits; track max-of-S per v (log is monotonic),
// one log at the end. clip(.,0,1) absorbs the gate-as-0 terms exactly.
__global__ __launch_bounds__(256) void k_rowstats(
    const __hip_bfloat16* __restrict__ Sb, const int* __restrict__ mask,
    float* __restrict__ RS, float* __restrict__ CONF)
{
    int n = blockIdx.x, tid = threadIdx.x;
    int lane = tid & 63, wv = tid >> 6;
    __shared__ unsigned int mb[NV][NN / 32];

    for (int ch = wv; ch < NN / 64; ch += 4) {
        int m = ch * 64 + lane;
#pragma unroll
        for (int v = 0; v < NV; ++v) {
            unsigned long long b = __ballot(mask[m * NV + v] != 0);
            if (lane == 0) {
                mb[v][2 * ch]     = (unsigned int)b;
                mb[v][2 * ch + 1] = (unsigned int)(b >> 32);
            }
        }
    }
    __syncthreads();

    float lsum = 0.0f;
    float mv0 = 0.0f, mv1 = 0.0f, mv2 = 0.0f;
    const uint4* S8 = (const uint4*)(Sb + (size_t)n * NN);
    for (int i = tid; i < NN / 8; i += 256) {
        uint4 u = S8[i];
        unsigned sh = (i & 3) * 8;
        unsigned b0 = (mb[0][i >> 2] >> sh) & 0xffu;
        unsigned b1 = (mb[1][i >> 2] >> sh) & 0xffu;
        unsigned b2 = (mb[2][i >> 2] >> sh) & 0xffu;
        float f[8] = { bf2f(u.x & 0xffff), bf2f(u.x >> 16),
                       bf2f(u.y & 0xffff), bf2f(u.y >> 16),
                       bf2f(u.z & 0xffff), bf2f(u.z >> 16),
                       bf2f(u.w & 0xffff), bf2f(u.w >> 16) };
#pragma unroll
        for (int j = 0; j < 8; ++j) {
            lsum += f[j];
            mv0 = fmaxf(mv0, ((b0 >> j) & 1) ? f[j] : 0.0f);
            mv1 = fmaxf(mv1, ((b1 >> j) & 1) ? f[j] : 0.0f);
            mv2 = fmaxf(mv2, ((b2 >> j) & 1) ? f[j] : 0.0f);
        }
    }
    __shared__ float ssum[4];
    __shared__ float smax[4][NV];
    float mv[NV] = { mv0, mv1, mv2 };
#pragma unroll
    for (int off = 32; off > 0; off >>= 1) {
        lsum += __shfl_down(lsum, off, 64);
#pragma unroll
        for (int v = 0; v < NV; ++v)
            mv[v] = fmaxf(mv[v], __shfl_down(mv[v], off, 64));
    }
    if (lane == 0) {
        ssum[wv] = lsum;
#pragma unroll
        for (int v = 0; v < NV; ++v) smax[wv][v] = mv[v];
    }
    __syncthreads();
    if (tid == 0) RS[n] = ssum[0] + ssum[1] + ssum[2] + ssum[3];
    if (tid < NV) {
        float cm = fmaxf(fmaxf(smax[0][tid], smax[1][tid]),
                         fmaxf(smax[2][tid], smax[3][tid]));
        float lg = 0.2f * __logf(cm + 1e-9f);
        CONF[tid * NN + n] = fminf(fmaxf(lg, 0.0f), 1.0f);
    }
}

// ---------------------------------------------------------------- k_newx
// 128x128 tile, 2-phase dbuf pipeline, K=4096.
// FUSED: write Z directly (new_x * y_n), no NX round-trip, no k_z.
// YN read straight from global in the epilogue (20 KB, L1/L2-resident) to
// keep LDS at 66.5 KB -> 2 blocks/CU.
template<bool FUSED>
__global__ __launch_bounds__(256) void k_newx_t(
    const __hip_bfloat16* __restrict__ Sb, const __hip_bfloat16* __restrict__ XPMT,
    const float* __restrict__ XP, const float* __restrict__ RS,
    const int* __restrict__ mask, const float* __restrict__ YN,
    float* __restrict__ Out)   // FUSED ? Z : NX
{
    int v  = blockIdx.z;
    int n0 = blockIdx.x * 128, h0 = blockIdx.y * 128;
    int tid = threadIdx.x, lane = tid & 63, wid = tid >> 6;
    int wr = (wid >> 1) * 64, wc = (wid & 1) * 64;
    int rowA = lane & 31, hi = lane >> 5;

    __shared__ __align__(128) char Ash[2][16384];
    __shared__ __align__(128) char Bsh[2][16384];
    __shared__ int   mn[128];
    __shared__ float rsn[128];

    if (tid < 128) {
        mn[tid]  = mask[(n0 + tid) * NV + v];
        rsn[tid] = 1.0f / (RS[n0 + tid] + 1e-9f);
    }

    v16f acc[2][2];
#pragma unroll
    for (int i = 0; i < 2; ++i)
#pragma unroll
        for (int j = 0; j < 2; ++j) acc[i][j] = (v16f)0.0f;

    const __bf16* Apanel = (const __bf16*)Sb + (size_t)n0 * NN;
    const __bf16* Bpanel = (const __bf16*)XPMT + ((size_t)v * HH + h0) * NN;

    stage_tile(Apanel, NN, Ash[0], tid);
    stage_tile(Bpanel, NN, Bsh[0], tid);
    __syncthreads();

    int cur = 0;
#pragma unroll 1
    for (int t = 0; t < NN / 64; ++t) {
        if (t < NN / 64 - 1) {
            stage_tile(Apanel + (t + 1) * 64, NN, Ash[cur ^ 1], tid);
            stage_tile(Bpanel + (t + 1) * 64, NN, Bsh[cur ^ 1], tid);
        }
#pragma unroll
        for (int kk = 0; kk < 4; ++kk) {
            int q = kk * 2 + hi;
            v8bf af[2], bfr[2];
#pragma unroll
            for (int tt = 0; tt < 2; ++tt) {
                af[tt]  = frag_read(Ash[cur], wr + tt * 32 + rowA, q);
                bfr[tt] = frag_read(Bsh[cur], wc + tt * 32 + rowA, q);
            }
#pragma unroll
            for (int i = 0; i < 2; ++i)
#pragma unroll
                for (int j = 0; j < 2; ++j)
                    acc[i][j] = __builtin_amdgcn_mfma_f32_32x32x16_bf16(
                        af[i], bfr[j], acc[i][j], 0, 0, 0);
        }
        __syncthreads();
        cur ^= 1;
    }

#pragma unroll
    for (int i = 0; i < 2; ++i)
#pragma unroll
        for (int j = 0; j < 2; ++j) {
            int h = h0 + wc + j * 32 + rowA;
            float val[16];
#pragma unroll
            for (int r = 0; r < 16; ++r) {
                int rown = wr + i * 32 + (r & 3) + 8 * (r >> 2) + 4 * hi;
                size_t o = ((size_t)v * NN + n0 + rown) * HH + h;
                val[r] = mn[rown] ? XP[o] : acc[i][j][r] * rsn[rown];
            }
            if (FUSED) {
                const float* ynp = YN + h;
#pragma unroll 1
                for (int c = 0; c < CC; ++c) {
                    float ynv = ynp[c * HH];
#pragma unroll
                    for (int r = 0; r < 16; ++r) {
                        int rown = wr + i * 32 + (r & 3) + 8 * (r >> 2) + 4 * hi;
                        size_t zo = (((size_t)v * NN + n0 + rown) * CC + c) * HH + h;
                        Out[zo] = val[r] * ynv;
                    }
                }
            } else {
#pragma unroll
                for (int r = 0; r < 16; ++r) {
                    int rown = wr + i * 32 + (r & 3) + 8 * (r >> 2) + 4 * hi;
                    size_t o = ((size_t)v * NN + n0 + rown) * HH + h;
                    Out[o] = val[r];
                }
            }
        }
}

// ---------------------------------------------------------------- k_z (fallback)
__global__ __launch_bounds__(256) void k_z(
    const float* __restrict__ NX, const float* __restrict__ YN,
    float* __restrict__ Z)
{
    int blk = blockIdx.x;
    int tid = threadIdx.x;
    int r = tid >> 6, h4 = (tid & 63) * 4;
    size_t row = (size_t)blk * 4 + r;
    float4 nx = *(const float4*)&NX[row * HH + h4];
    size_t base = row * CC * HH + h4;
#pragma unroll
    for (int c = 0; c < CC; ++c) {
        float4 yn = *(const float4*)&YN[c * HH + h4];
        float4 o;
        o.x = nx.x * yn.x; o.y = nx.y * yn.y;
        o.z = nx.z * yn.z; o.w = nx.w * yn.w;
        *(float4*)&Z[base + (size_t)c * HH] = o;
    }
}

// ---------------------------------------------------------------- launch
extern "C" void kernel_launch(void* const* d_in, const int* in_sizes, int n_in,
                              void* d_out, int out_size, void* d_ws, size_t ws_size,
                              hipStream_t stream)
{
    (void)in_sizes; (void)n_in; (void)out_size;
    const float* x0 = (const float*)d_in[0];
    const float* W0 = (const float*)d_in[1];
    const float* b0 = (const float*)d_in[2];
    const float* x1 = (const float*)d_in[3];
    const float* W1 = (const float*)d_in[4];
    const float* b1 = (const float*)d_in[5];
    const float* x2 = (const float*)d_in[6];
    const float* W2 = (const float*)d_in[7];
    const float* b2 = (const float*)d_in[8];
    const float* y  = (const float*)d_in[9];
    const float* Wy = (const float*)d_in[10];
    const float* by = (const float*)d_in[11];
    const int* mask = (const int*)d_in[12];
    float* out = (float*)d_out;
    float* CONF = out + (size_t)NV * NN * CC * HH;

    // Fused-path ws layout (bytes):
    //   Sb   bf16 NN*NN      @ 0          33,554,432
    //   XPMT bf16 V*H*N      @ 33554432    6,291,456
    //   XQh  bf16 V*N*H      @ 39845888    6,291,456
    //   XP   f32  V*N*H      @ 46137344   12,582,912
    //   RS   f32  N          @ 58720256       16,384
    //   YN   f32  C*H        @ 58736640       81,920
    //   total 58,818,560
    const size_t WS_NEED = 58818560u;

    if (ws_size >= WS_NEED) {
        char* w = (char*)d_ws;
        __hip_bfloat16* Sb   = (__hip_bfloat16*)w;
        __hip_bfloat16* XPMT = (__hip_bfloat16*)(w + 33554432);
        __hip_bfloat16* XQh  = (__hip_bfloat16*)(w + 39845888);
        float*          XP   = (float*)(w + 46137344);
        float*          RS   = (float*)(w + 58720256);
        float*          YN   = (float*)(w + 58736640);

        k_yn<<<CC, 256, 0, stream>>>(y, Wy, by, YN);
        k_proj<<<NV * NN / 8, 256, 0, stream>>>(x0, x1, x2, W0, W1, W2,
                                                b0, b1, b2, mask, XP, XQh, XPMT);
        const int T = NN / 128;
        k_scores<<<T * (T + 1) / 2, 256, 0, stream>>>(XQh, mask, Sb);
        k_rowstats<<<NN, 256, 0, stream>>>(Sb, mask, RS, CONF);
        dim3 gn(NN / 128, HH / 128, NV);
        k_newx_t<true><<<gn, 256, 0, stream>>>(Sb, XPMT, XP, RS, mask, YN, out);
    } else {
        // Fallback: scratch carved from out's Z region (dead until k_z),
        // NX/RS/YN in ws (~12.7 MB).
        __hip_bfloat16* Sb   = (__hip_bfloat16*)out;
        float*          XP   = out + 8388608;
        __hip_bfloat16* XQh  = (__hip_bfloat16*)(out + 11534336);
        __hip_bfloat16* XPMT = (__hip_bfloat16*)(out + 13107200);
        float* NX = (float*)d_ws;
        float* RS = NX + (size_t)NV * NN * HH;
        float* YN = RS + NN;

        k_yn<<<CC, 256, 0, stream>>>(y, Wy, by, YN);
        k_proj<<<NV * NN / 8, 256, 0, stream>>>(x0, x1, x2, W0, W1, W2,
                                                b0, b1, b2, mask, XP, XQh, XPMT);
        const int T = NN / 128;
        k_scores<<<T * (T + 1) / 2, 256, 0, stream>>>(XQh, mask, Sb);
        k_rowstats<<<NN, 256, 0, stream>>>(Sb, mask, RS, CONF);
        dim3 gn(NN / 128, HH / 128, NV);
        k_newx_t<false><<<gn, 256, 0, stream>>>(Sb, XPMT, XP, RS, mask, YN, NX);
        k_z<<<NV * NN / 4, 256, 0, stream>>>(NX, YN, out);
    }
}

// Round 4
// 561.755 us; speedup vs baseline: 1.0199x; 1.0199x over previous
//
#include <hip/hip_runtime.h>
#include <hip/hip_bf16.h>
#include <cstdint>

#define NV 3
#define NN 4096
#define HH 256
#define CC 20
#define DYY 300
#define DD 512

typedef __bf16 v8bf  __attribute__((ext_vector_type(8)));
typedef float  v16f  __attribute__((ext_vector_type(16)));

static __device__ __forceinline__ float bf2f(unsigned short u) {
    union { unsigned int i; float f; } c; c.i = ((unsigned int)u) << 16; return c.f;
}

// Stage a 128x64 bf16 tile into a 16 KB LDS buffer via global_load_lds w=16.
// LDS dest linear (HW requirement); XOR swizzle (chunk ^= row&7) applied on the
// GLOBAL source side, matching XOR on ds_read (rule #21).
static __device__ __forceinline__ void stage_tile(const __bf16* src, int strideElems,
                                                  char* lds, int tid)
{
#pragma unroll
    for (int i = 0; i < 4; ++i) {
        int id = i * 256 + tid;          // 16 B chunk id, 0..1023
        int r = id >> 3, c = id & 7;
        const char* g = (const char*)(src + (size_t)r * strideElems)
                        + ((c ^ (r & 7)) << 4);
        __builtin_amdgcn_global_load_lds(
            (const __attribute__((address_space(1))) unsigned int*)g,
            (__attribute__((address_space(3))) unsigned int*)(lds + id * 16),
            16, 0, 0);
    }
}

// Stage a 64x64 bf16 tile (8 KB, 512 chunks) — same swizzle scheme.
static __device__ __forceinline__ void stage_tile64(const __bf16* src, int strideElems,
                                                    char* lds, int tid)
{
#pragma unroll
    for (int i = 0; i < 2; ++i) {
        int id = i * 256 + tid;          // 16 B chunk id, 0..511
        int r = id >> 3, c = id & 7;
        const char* g = (const char*)(src + (size_t)r * strideElems)
                        + ((c ^ (r & 7)) << 4);
        __builtin_amdgcn_global_load_lds(
            (const __attribute__((address_space(1))) unsigned int*)g,
            (__attribute__((address_space(3))) unsigned int*)(lds + id * 16),
            16, 0, 0);
    }
}

static __device__ __forceinline__ v8bf frag_read(const char* lds, int ra, int q)
{
    return *(const v8bf*)(lds + ra * 128 + ((q ^ (ra & 7)) << 4));
}

// ---------------------------------------------------------------- k_yn
__global__ __launch_bounds__(256) void k_yn(
    const float* __restrict__ y, const float* __restrict__ Wy,
    const float* __restrict__ by, float* __restrict__ YN)
{
    __shared__ __align__(16) float ysh[DYY];
    int c = blockIdx.x, tid = threadIdx.x;
    for (int i = tid; i < DYY; i += 256) ysh[i] = y[c * DYY + i];
    __syncthreads();
    float acc = by[tid];
    const float4* Wr4 = (const float4*)(Wy + (size_t)tid * DYY);
    const float4* ys4 = (const float4*)ysh;
    for (int d4 = 0; d4 < DYY / 4; ++d4) {
        float4 w = Wr4[d4], yy = ys4[d4];
        acc = fmaf(yy.x, w.x, acc); acc = fmaf(yy.y, w.y, acc);
        acc = fmaf(yy.z, w.z, acc); acc = fmaf(yy.w, w.w, acc);
    }
    YN[c * HH + tid] = 1.0f / (1.0f + __expf(-acc));
}

// ---------------------------------------------------------------- k_proj
// R=32 rows/block: W_v re-read per block drops 4x vs R=8 (6.4 GB -> 1.6 GB L2).
__global__ __launch_bounds__(256) void k_proj(
    const float* __restrict__ x0, const float* __restrict__ x1, const float* __restrict__ x2,
    const float* __restrict__ W0, const float* __restrict__ W1, const float* __restrict__ W2,
    const float* __restrict__ b0, const float* __restrict__ b1, const float* __restrict__ b2,
    const int* __restrict__ mask,
    float* __restrict__ XP, __hip_bfloat16* __restrict__ XQh,
    __hip_bfloat16* __restrict__ XPMT)
{
    const int R = 32;
    int tid = threadIdx.x;
    int blk = blockIdx.x;
    int v  = blk / (NN / R);
    int n0 = (blk % (NN / R)) * R;
    const float* xv = (v == 0) ? x0 : (v == 1 ? x1 : x2);
    const float* Wv = (v == 0) ? W0 : (v == 1 ? W1 : W2);
    const float* bv = (v == 0) ? b0 : (v == 1 ? b1 : b2);

    __shared__ __align__(16) float xsh[R][DD];     // 64 KB
    __shared__ float wred[4][R];
    __shared__ float nrm_sh[R];
    __shared__ int   msk_sh[R];

    const float4* xsrc = (const float4*)(xv + (size_t)n0 * DD);
    for (int i = tid; i < R * DD / 4; i += 256)
        ((float4*)xsh)[i] = xsrc[i];
    if (tid < R) msk_sh[tid] = mask[(n0 + tid) * NV + v];
    __syncthreads();

    float acc[R];
#pragma unroll
    for (int r = 0; r < R; ++r) acc[r] = 0.0f;
    const float4* Wrow = (const float4*)(Wv + (size_t)tid * DD);
#pragma unroll 2
    for (int d4 = 0; d4 < DD / 4; ++d4) {
        float4 w = Wrow[d4];
#pragma unroll
        for (int r = 0; r < R; ++r) {
            acc[r] = fmaf(xsh[r][4 * d4 + 0], w.x, acc[r]);
            acc[r] = fmaf(xsh[r][4 * d4 + 1], w.y, acc[r]);
            acc[r] = fmaf(xsh[r][4 * d4 + 2], w.z, acc[r]);
            acc[r] = fmaf(xsh[r][4 * d4 + 3], w.w, acc[r]);
        }
    }
    float bb = bv[tid];
    float vals[R];
#pragma unroll
    for (int r = 0; r < R; ++r) {
        float t = acc[r] + bb;
        vals[r] = (t >= 0.0f) ? t : 0.1f * t;
    }
    int lane = tid & 63, wv = tid >> 6;
#pragma unroll
    for (int r = 0; r < R; ++r) {
        float sq = vals[r] * vals[r];
#pragma unroll
        for (int off = 32; off > 0; off >>= 1)
            sq += __shfl_down(sq, off, 64);
        if (lane == 0) wred[wv][r] = sq;
    }
    __syncthreads();
    if (tid < R) {
        float s = wred[0][tid] + wred[1][tid] + wred[2][tid] + wred[3][tid];
        nrm_sh[tid] = fmaxf(sqrtf(s), 1e-12f);
    }
    __syncthreads();
#pragma unroll
    for (int r = 0; r < R; ++r) {
        size_t o = ((size_t)v * NN + n0 + r) * HH + tid;
        float xpv = vals[r];
        XP[o]  = xpv;
        XQh[o] = __float2bfloat16(xpv / nrm_sh[r]);
    }
#pragma unroll
    for (int g = 0; g < R / 8; ++g) {
        union { __hip_bfloat16 h[8]; uint4 u; } pk;
#pragma unroll
        for (int r = 0; r < 8; ++r)
            pk.h[r] = __float2bfloat16(msk_sh[g * 8 + r] ? vals[g * 8 + r] : 0.0f);
        *(uint4*)&XPMT[((size_t)v * HH + tid) * NN + n0 + g * 8] = pk.u;
    }
}

// ---------------------------------------------------------------- k_scores
// Upper-triangular 128x128 tiles, mirror-write transpose. 2-phase dbuf
// pipeline: stage(s+1) issued BEFORE compute(s); one drain per phase.
__global__ __launch_bounds__(256) void k_scores(
    const __hip_bfloat16* __restrict__ XQh, const int* __restrict__ mask,
    __hip_bfloat16* __restrict__ Sb)
{
    const int T = NN / 128;
    int rem = blockIdx.x, bi = 0;
    while (rem >= T - bi) { rem -= T - bi; ++bi; }
    int bj = bi + rem;
    int n0 = bi * 128, m0 = bj * 128;

    int tid = threadIdx.x, lane = tid & 63, wid = tid >> 6;
    int wr = (wid >> 1) * 64, wc = (wid & 1) * 64;
    int rowA = lane & 31, hi = lane >> 5;

    __shared__ __align__(128) char Ash[2][16384];
    __shared__ __align__(128) char Bsh[2][16384];
    __shared__ int mnsh[NV][128], mmsh[NV][128];

    if (tid < 128) {
#pragma unroll
        for (int v = 0; v < NV; ++v) {
            mnsh[v][tid] = mask[(n0 + tid) * NV + v];
            mmsh[v][tid] = mask[(m0 + tid) * NV + v];
        }
    }

    float comb[2][2][16];
#pragma unroll
    for (int i = 0; i < 2; ++i)
#pragma unroll
        for (int j = 0; j < 2; ++j)
#pragma unroll
            for (int r = 0; r < 16; ++r) comb[i][j][r] = -1e30f;

    v16f acc[2][2];
#pragma unroll
    for (int i = 0; i < 2; ++i)
#pragma unroll
        for (int j = 0; j < 2; ++j) acc[i][j] = (v16f)0.0f;

    const __bf16* Abase = (const __bf16*)XQh + (size_t)n0 * HH;
    const __bf16* Bbase = (const __bf16*)XQh + (size_t)m0 * HH;
    const size_t vstep = (size_t)NN * HH;

    stage_tile(Abase, HH, Ash[0], tid);
    stage_tile(Bbase, HH, Bsh[0], tid);
    __syncthreads();

    int cur = 0;
#pragma unroll 1
    for (int s = 0; s < 12; ++s) {
        if (s < 11) {
            int sn = s + 1, vn = sn >> 2, kn = (sn & 3) * 64;
            stage_tile(Abase + (size_t)vn * vstep + kn, HH, Ash[cur ^ 1], tid);
            stage_tile(Bbase + (size_t)vn * vstep + kn, HH, Bsh[cur ^ 1], tid);
        }
#pragma unroll
        for (int kk = 0; kk < 4; ++kk) {
            int q = kk * 2 + hi;
            v8bf af[2], bfr[2];
#pragma unroll
            for (int t = 0; t < 2; ++t) {
                af[t]  = frag_read(Ash[cur], wr + t * 32 + rowA, q);
                bfr[t] = frag_read(Bsh[cur], wc + t * 32 + rowA, q);
            }
#pragma unroll
            for (int i = 0; i < 2; ++i)
#pragma unroll
                for (int j = 0; j < 2; ++j)
                    acc[i][j] = __builtin_amdgcn_mfma_f32_32x32x16_bf16(
                        af[i], bfr[j], acc[i][j], 0, 0, 0);
        }
        if ((s & 3) == 3) {
            int v = s >> 2;
#pragma unroll
            for (int i = 0; i < 2; ++i)
#pragma unroll
                for (int j = 0; j < 2; ++j) {
                    int cm = mmsh[v][wc + j * 32 + rowA];
#pragma unroll
                    for (int r = 0; r < 16; ++r) {
                        int rown = wr + i * 32 + (r & 3) + 8 * (r >> 2) + 4 * hi;
                        float g = (cm && mnsh[v][rown]) ? acc[i][j][r] : -1e30f;
                        comb[i][j][r] = fmaxf(comb[i][j][r], g);
                    }
                    acc[i][j] = (v16f)0.0f;
                }
        }
        __syncthreads();
        cur ^= 1;
    }

#pragma unroll
    for (int i = 0; i < 2; ++i)
#pragma unroll
        for (int j = 0; j < 2; ++j) {
            int m = m0 + wc + j * 32 + rowA;
            float sv[16];
#pragma unroll
            for (int r = 0; r < 16; ++r) {
                int rown = wr + i * 32 + (r & 3) + 8 * (r >> 2) + 4 * hi;
                float e = __expf(comb[i][j][r] * 5.0f);
                if (n0 + rown == m) e = 0.0f;
                sv[r] = e;
                Sb[(size_t)(n0 + rown) * NN + m] = __float2bfloat16(e);
            }
            if (bi != bj) {
#pragma unroll
                for (int g4 = 0; g4 < 4; ++g4) {
                    union { __hip_bfloat16 h[4]; uint2 u; } pk;
#pragma unroll
                    for (int j2 = 0; j2 < 4; ++j2)
                        pk.h[j2] = __float2bfloat16(sv[4 * g4 + j2]);
                    int nbase = n0 + wr + i * 32 + 8 * g4 + 4 * hi;
                    *(uint2*)((unsigned short*)Sb + (size_t)m * NN + nbase) = pk.u;
                }
            }
        }
}

// ---------------------------------------------------------------- k_rowstats
__global__ __launch_bounds__(256) void k_rowstats(
    const __hip_bfloat16* __restrict__ Sb, const int* __restrict__ mask,
    float* __restrict__ RS, float* __restrict__ CONF)
{
    int n = blockIdx.x, tid = threadIdx.x;
    int lane = tid & 63, wv = tid >> 6;
    __shared__ unsigned int mb[NV][NN / 32];

    for (int ch = wv; ch < NN / 64; ch += 4) {
        int m = ch * 64 + lane;
#pragma unroll
        for (int v = 0; v < NV; ++v) {
            unsigned long long b = __ballot(mask[m * NV + v] != 0);
            if (lane == 0) {
                mb[v][2 * ch]     = (unsigned int)b;
                mb[v][2 * ch + 1] = (unsigned int)(b >> 32);
            }
        }
    }
    __syncthreads();

    float lsum = 0.0f;
    float mv0 = 0.0f, mv1 = 0.0f, mv2 = 0.0f;
    const uint4* S8 = (const uint4*)(Sb + (size_t)n * NN);
    for (int i = tid; i < NN / 8; i += 256) {
        uint4 u = S8[i];
        unsigned sh = (i & 3) * 8;
        unsigned b0 = (mb[0][i >> 2] >> sh) & 0xffu;
        unsigned b1 = (mb[1][i >> 2] >> sh) & 0xffu;
        unsigned b2 = (mb[2][i >> 2] >> sh) & 0xffu;
        float f[8] = { bf2f(u.x & 0xffff), bf2f(u.x >> 16),
                       bf2f(u.y & 0xffff), bf2f(u.y >> 16),
                       bf2f(u.z & 0xffff), bf2f(u.z >> 16),
                       bf2f(u.w & 0xffff), bf2f(u.w >> 16) };
#pragma unroll
        for (int j = 0; j < 8; ++j) {
            lsum += f[j];
            mv0 = fmaxf(mv0, ((b0 >> j) & 1) ? f[j] : 0.0f);
            mv1 = fmaxf(mv1, ((b1 >> j) & 1) ? f[j] : 0.0f);
            mv2 = fmaxf(mv2, ((b2 >> j) & 1) ? f[j] : 0.0f);
        }
    }
    __shared__ float ssum[4];
    __shared__ float smax[4][NV];
    float mv[NV] = { mv0, mv1, mv2 };
#pragma unroll
    for (int off = 32; off > 0; off >>= 1) {
        lsum += __shfl_down(lsum, off, 64);
#pragma unroll
        for (int v = 0; v < NV; ++v)
            mv[v] = fmaxf(mv[v], __shfl_down(mv[v], off, 64));
    }
    if (lane == 0) {
        ssum[wv] = lsum;
#pragma unroll
        for (int v = 0; v < NV; ++v) smax[wv][v] = mv[v];
    }
    __syncthreads();
    if (tid == 0) RS[n] = ssum[0] + ssum[1] + ssum[2] + ssum[3];
    if (tid < NV) {
        float cm = fmaxf(fmaxf(smax[0][tid], smax[1][tid]),
                         fmaxf(smax[2][tid], smax[3][tid]));
        float lg = 0.2f * __logf(cm + 1e-9f);
        CONF[tid * NN + n] = fminf(fmaxf(lg, 0.0f), 1.0f);
    }
}

// ---------------------------------------------------------------- k_newx
// 64x64 tiles, grid (NN/64, HH/64, NV) = 768 blocks (~3-4 blocks/CU TLP).
// Wave = one 32x32 MFMA quadrant. 2-phase dbuf. LDS ~33 KB.
// FUSED: write Z directly (new_x * y_n), no NX round-trip, no k_z.
template<bool FUSED>
__global__ __launch_bounds__(256) void k_newx_t(
    const __hip_bfloat16* __restrict__ Sb, const __hip_bfloat16* __restrict__ XPMT,
    const float* __restrict__ XP, const float* __restrict__ RS,
    const int* __restrict__ mask, const float* __restrict__ YN,
    float* __restrict__ Out)   // FUSED ? Z : NX
{
    int v  = blockIdx.z;
    int n0 = blockIdx.x * 64, h0 = blockIdx.y * 64;
    int tid = threadIdx.x, lane = tid & 63, wid = tid >> 6;
    int wr = (wid >> 1) * 32, wc = (wid & 1) * 32;
    int rowA = lane & 31, hi = lane >> 5;

    __shared__ __align__(128) char Ash[2][8192];
    __shared__ __align__(128) char Bsh[2][8192];
    __shared__ int   mn[64];
    __shared__ float rsn[64];

    if (tid < 64) {
        mn[tid]  = mask[(n0 + tid) * NV + v];
        rsn[tid] = 1.0f / (RS[n0 + tid] + 1e-9f);
    }

    v16f acc = (v16f)0.0f;

    const __bf16* Apanel = (const __bf16*)Sb + (size_t)n0 * NN;
    const __bf16* Bpanel = (const __bf16*)XPMT + ((size_t)v * HH + h0) * NN;

    stage_tile64(Apanel, NN, Ash[0], tid);
    stage_tile64(Bpanel, NN, Bsh[0], tid);
    __syncthreads();

    int cur = 0;
#pragma unroll 1
    for (int t = 0; t < NN / 64; ++t) {
        if (t < NN / 64 - 1) {
            stage_tile64(Apanel + (t + 1) * 64, NN, Ash[cur ^ 1], tid);
            stage_tile64(Bpanel + (t + 1) * 64, NN, Bsh[cur ^ 1], tid);
        }
#pragma unroll
        for (int kk = 0; kk < 4; ++kk) {
            int q = kk * 2 + hi;
            v8bf a = frag_read(Ash[cur], wr + rowA, q);
            v8bf b = frag_read(Bsh[cur], wc + rowA, q);
            acc = __builtin_amdgcn_mfma_f32_32x32x16_bf16(a, b, acc, 0, 0, 0);
        }
        __syncthreads();
        cur ^= 1;
    }

    int h = h0 + wc + rowA;
    float val[16];
#pragma unroll
    for (int r = 0; r < 16; ++r) {
        int rown = wr + (r & 3) + 8 * (r >> 2) + 4 * hi;
        size_t o = ((size_t)v * NN + n0 + rown) * HH + h;
        val[r] = mn[rown] ? XP[o] : acc[r] * rsn[rown];
    }
    if (FUSED) {
        const float* ynp = YN + h;
#pragma unroll 1
        for (int c = 0; c < CC; ++c) {
            float ynv = ynp[c * HH];
#pragma unroll
            for (int r = 0; r < 16; ++r) {
                int rown = wr + (r & 3) + 8 * (r >> 2) + 4 * hi;
                size_t zo = (((size_t)v * NN + n0 + rown) * CC + c) * HH + h;
                Out[zo] = val[r] * ynv;
            }
        }
    } else {
#pragma unroll
        for (int r = 0; r < 16; ++r) {
            int rown = wr + (r & 3) + 8 * (r >> 2) + 4 * hi;
            size_t o = ((size_t)v * NN + n0 + rown) * HH + h;
            Out[o] = val[r];
        }
    }
}

// ---------------------------------------------------------------- k_z (fallback)
__global__ __launch_bounds__(256) void k_z(
    const float* __restrict__ NX, const float* __restrict__ YN,
    float* __restrict__ Z)
{
    int blk = blockIdx.x;
    int tid = threadIdx.x;
    int r = tid >> 6, h4 = (tid & 63) * 4;
    size_t row = (size_t)blk * 4 + r;
    float4 nx = *(const float4*)&NX[row * HH + h4];
    size_t base = row * CC * HH + h4;
#pragma unroll
    for (int c = 0; c < CC; ++c) {
        float4 yn = *(const float4*)&YN[c * HH + h4];
        float4 o;
        o.x = nx.x * yn.x; o.y = nx.y * yn.y;
        o.z = nx.z * yn.z; o.w = nx.w * yn.w;
        *(float4*)&Z[base + (size_t)c * HH] = o;
    }
}

// ---------------------------------------------------------------- launch
extern "C" void kernel_launch(void* const* d_in, const int* in_sizes, int n_in,
                              void* d_out, int out_size, void* d_ws, size_t ws_size,
                              hipStream_t stream)
{
    (void)in_sizes; (void)n_in; (void)out_size;
    const float* x0 = (const float*)d_in[0];
    const float* W0 = (const float*)d_in[1];
    const float* b0 = (const float*)d_in[2];
    const float* x1 = (const float*)d_in[3];
    const float* W1 = (const float*)d_in[4];
    const float* b1 = (const float*)d_in[5];
    const float* x2 = (const float*)d_in[6];
    const float* W2 = (const float*)d_in[7];
    const float* b2 = (const float*)d_in[8];
    const float* y  = (const float*)d_in[9];
    const float* Wy = (const float*)d_in[10];
    const float* by = (const float*)d_in[11];
    const int* mask = (const int*)d_in[12];
    float* out = (float*)d_out;
    float* CONF = out + (size_t)NV * NN * CC * HH;

    const size_t WS_NEED = 58818560u;

    if (ws_size >= WS_NEED) {
        char* w = (char*)d_ws;
        __hip_bfloat16* Sb   = (__hip_bfloat16*)w;
        __hip_bfloat16* XPMT = (__hip_bfloat16*)(w + 33554432);
        __hip_bfloat16* XQh  = (__hip_bfloat16*)(w + 39845888);
        float*          XP   = (float*)(w + 46137344);
        float*          RS   = (float*)(w + 58720256);
        float*          YN   = (float*)(w + 58736640);

        k_yn<<<CC, 256, 0, stream>>>(y, Wy, by, YN);
        k_proj<<<NV * NN / 32, 256, 0, stream>>>(x0, x1, x2, W0, W1, W2,
                                                 b0, b1, b2, mask, XP, XQh, XPMT);
        const int T = NN / 128;
        k_scores<<<T * (T + 1) / 2, 256, 0, stream>>>(XQh, mask, Sb);
        k_rowstats<<<NN, 256, 0, stream>>>(Sb, mask, RS, CONF);
        dim3 gn(NN / 64, HH / 64, NV);
        k_newx_t<true><<<gn, 256, 0, stream>>>(Sb, XPMT, XP, RS, mask, YN, out);
    } else {
        __hip_bfloat16* Sb   = (__hip_bfloat16*)out;
        float*          XP   = out + 8388608;
        __hip_bfloat16* XQh  = (__hip_bfloat16*)(out + 11534336);
        __hip_bfloat16* XPMT = (__hip_bfloat16*)(out + 13107200);
        float* NX = (float*)d_ws;
        float* RS = NX + (size_t)NV * NN * HH;
        float* YN = RS + NN;

        k_yn<<<CC, 256, 0, stream>>>(y, Wy, by, YN);
        k_proj<<<NV * NN / 32, 256, 0, stream>>>(x0, x1, x2, W0, W1, W2,
                                                 b0, b1, b2, mask, XP, XQh, XPMT);
        const int T = NN / 128;
        k_scores<<<T * (T + 1) / 2, 256, 0, stream>>>(XQh, mask, Sb);
        k_rowstats<<<NN, 256, 0, stream>>>(Sb, mask, RS, CONF);
        dim3 gn(NN / 64, HH / 64, NV);
        k_newx_t<false><<<gn, 256, 0, stream>>>(Sb, XPMT, XP, RS, mask, YN, NX);
        k_z<<<NV * NN / 4, 256, 0, stream>>>(NX, YN, out);
    }
}